// Round 7
// baseline (1299.641 us; speedup 1.0000x reference)
//
#include <hip/hip_runtime.h>

#define N_NODES 100000
#define N_EDGES 1600000
#define DIM 128
#define LEAKY 0.01f
#define RS_STRIDE 132
#define WS_STRIDE 132

#define NB_NODES 196     // nodes per bucket
#define NBUCKET 511      // ceil(100000/196)
#define SB_EDGES 4096    // edges per sort_local block
#define NSB 391          // ceil(1600000/4096)
#define AGG_ROWS 208     // 13 MFMA tiles x 16 rows
#define AGG_STRIDE 129   // +1 pad: LDS bank decorrelation

typedef short bf16x8 __attribute__((ext_vector_type(8)));
typedef float f32x4 __attribute__((ext_vector_type(4)));

static __device__ __forceinline__ unsigned short f2bf(float f) {
  unsigned int u = __float_as_uint(f);
  u = (u + 0x7fffu + ((u >> 16) & 1u)) >> 16;  // RNE
  return (unsigned short)u;
}

// ---------------------------------------------------------------------------
// K1: local bucket sort. Each block takes 4096 edges, histograms bucket
// (= dst/196, 511 buckets), scans in LDS, stages bucket-sorted records in
// LDS, writes coalesced runs. Record: {src | localD<<17, attr}.
// Emits counts[b][sb] (ushort) and srcOff[b][sb] (run start in binned).
// ---------------------------------------------------------------------------
__global__ __launch_bounds__(512) void sort_local_kernel(
    const int* __restrict__ ei, const float* __restrict__ attr,
    int2* __restrict__ binned, unsigned short* __restrict__ counts,
    int* __restrict__ srcOff) {
  __shared__ int hist[NBUCKET];
  __shared__ int cursor[NBUCKET];
  __shared__ int scanBuf[512];
  __shared__ int2 stage[SB_EDGES];  // 32 KB

  const int t = threadIdx.x;
  const int blk = blockIdx.x;
  const int base = blk * SB_EDGES;
  const int n = min(SB_EDGES, N_EDGES - base);

  if (t < NBUCKET) hist[t] = 0;
  __syncthreads();

  int myP[8];
  int myB[8];
  float myA[8];
#pragma unroll
  for (int k = 0; k < 8; ++k) {
    int i = t + k * 512;
    if (i < n) {
      int e = base + i;
      int s = ei[e];
      int d = ei[N_EDGES + e];
      myA[k] = attr[e];
      unsigned int b = (unsigned int)d / NB_NODES;
      int ld = d - (int)b * NB_NODES;   // 0..195
      myB[k] = (int)b;
      myP[k] = s | (ld << 17);
      atomicAdd(&hist[b], 1);
    } else {
      myB[k] = -1;
    }
  }
  __syncthreads();

  int v = (t < NBUCKET) ? hist[t] : 0;
  scanBuf[t] = v;
  __syncthreads();
  for (int off = 1; off < 512; off <<= 1) {
    int u = (t >= off) ? scanBuf[t - off] : 0;
    __syncthreads();
    scanBuf[t] += u;
    __syncthreads();
  }
  if (t < NBUCKET) {
    int excl = scanBuf[t] - v;
    cursor[t] = excl;
    counts[(size_t)t * NSB + blk] = (unsigned short)v;
    srcOff[(size_t)t * NSB + blk] = base + excl;
  }
  __syncthreads();

#pragma unroll
  for (int k = 0; k < 8; ++k) {
    if (myB[k] >= 0) {
      int loc = atomicAdd(&cursor[myB[k]], 1);
      stage[loc] = make_int2(myP[k], __float_as_int(myA[k]));
    }
  }
  __syncthreads();

  for (int i = t; i < n; i += 512) binned[base + i] = stage[i];
}

// ---------------------------------------------------------------------------
// K2: x -> bf16, permuted: xb[n*64 + j] = pack(bf16(x[n][j]), bf16(x[n][j+64]))
// so gather lane j's dword covers feats {j, j+64} -> conflict-free LDS atomics.
// ---------------------------------------------------------------------------
__global__ __launch_bounds__(256) void x2b_perm_kernel(
    const float* __restrict__ x, unsigned int* __restrict__ xb) {
  const int gid = blockIdx.x * 256 + threadIdx.x;  // 6.4M exactly
  const int nn = gid >> 6;
  const int j = gid & 63;
  float f0 = x[(size_t)nn * DIM + j];
  float f1 = x[(size_t)nn * DIM + j + 64];
  xb[gid] = (unsigned int)f2bf(f0) | ((unsigned int)f2bf(f1) << 16);
}

// ---------------------------------------------------------------------------
// K3: W^T -> MFMA B-fragments (bf16, lane order), 8 blocks x 256.
// ---------------------------------------------------------------------------
__global__ __launch_bounds__(256) void w_frag_kernel(
    const float* __restrict__ W, bf16x8* __restrict__ wfrag) {
  const int gid = blockIdx.x * 256 + threadIdx.x;  // 0..2047
  const int lane = gid & 63;
  const int q = (gid >> 6) & 3;
  const int nt = gid >> 8;
  const int n = nt * 16 + (lane & 15);
  const int kb = q * 32 + ((lane >> 4) & 3) * 8;
  const float4 f0 = *(const float4*)(W + n * DIM + kb);
  const float4 f1 = *(const float4*)(W + n * DIM + kb + 4);
  bf16x8 frag;
  frag[0] = (short)f2bf(f0.x); frag[1] = (short)f2bf(f0.y);
  frag[2] = (short)f2bf(f0.z); frag[3] = (short)f2bf(f0.w);
  frag[4] = (short)f2bf(f1.x); frag[5] = (short)f2bf(f1.y);
  frag[6] = (short)f2bf(f1.z); frag[7] = (short)f2bf(f1.w);
  wfrag[gid] = frag;
}

// ---------------------------------------------------------------------------
// K4: fused bucket gather + MFMA linear. One block (1024 thr = 16 waves)
// per 196-node bucket. Phase 1: stream this bucket's binned runs, accumulate
// x[src]*attr into a 196x128 fp32 LDS tile via ds_add_f32 (lane->feat layout
// makes atomics 2-way bank = free). Phase 2: MFMA linear straight from LDS,
// LeakyReLU epilogue, store to out. No csr, no agg round-trip, no memsets.
// ---------------------------------------------------------------------------
__global__ __launch_bounds__(1024) void fused_kernel(
    const unsigned int* __restrict__ xb, const int2* __restrict__ binned,
    const unsigned short* __restrict__ counts, const int* __restrict__ srcOff,
    const bf16x8* __restrict__ wfrag, const float* __restrict__ bias,
    float* __restrict__ out) {
  __shared__ float aggS[AGG_ROWS * AGG_STRIDE];  // 107 KB
  __shared__ int runPrefix[NSB + 1];
  __shared__ int runSrc[NSB];
  __shared__ int scanBuf[1024];

  const int t = threadIdx.x;
  const int b = blockIdx.x;
  const int lane = t & 63;
  const int wave = t >> 6;  // 0..15

  // ---- run table + scan (inclusive Hillis-Steele over 1024, window 512) ----
  int len = (t < NSB) ? (int)counts[(size_t)b * NSB + t] : 0;
  if (t < NSB) runSrc[t] = srcOff[(size_t)b * NSB + t];
  scanBuf[t] = len;
  // ---- zero agg tile while scan barriers run ----
  __syncthreads();
  for (int off = 1; off <= 256; off <<= 1) {
    int u = (t >= off) ? scanBuf[t - off] : 0;
    __syncthreads();
    scanBuf[t] += u;
    __syncthreads();
  }
  if (t < NSB) runPrefix[t] = scanBuf[t] - len;
  if (t == NSB - 1) runPrefix[NSB] = scanBuf[t];
  {
    float2* az = (float2*)aggS;
    const int tot2 = (AGG_ROWS * AGG_STRIDE) / 2;  // 13416
#pragma unroll
    for (int k = 0; k < 14; ++k) {
      int i = t + k * 1024;
      if (i < tot2) az[i] = make_float2(0.f, 0.f);
    }
    if (t == 0) aggS[AGG_ROWS * AGG_STRIDE - 1] = 0.f;  // odd remainder? (even; harmless)
  }
  __syncthreads();

  // ---- phase 1: gather ----
  const int T = runPrefix[NSB];
  const int chunk = (T + 15) >> 4;
  int idx = wave * chunk;
  const int iend = min(T, idx + chunk);

  int r = 0;
  if (idx < iend) {
    int lo = 0, hi = NSB - 1;
    while (lo < hi) {
      int mid = (lo + hi + 1) >> 1;
      if (runPrefix[mid] <= idx) lo = mid; else hi = mid - 1;
    }
    r = lo;
  }

  while (idx < iend) {
    const int n8 = min(8, iend - idx);
    unsigned int uv[8];
    float av[8];
    int ldv[8];
#pragma unroll
    for (int k = 0; k < 8; ++k) {
      if (k < n8) {
        int i = idx + k;
        while (runPrefix[r + 1] <= i) ++r;  // monotone advance, amortized O(1)
        int2 rc = binned[runSrc[r] + (i - runPrefix[r])];
        ldv[k] = rc.x >> 17;
        av[k] = __int_as_float(rc.y);
        uv[k] = xb[(size_t)(rc.x & 0x1FFFF) * 64 + lane];
      }
    }
#pragma unroll
    for (int k = 0; k < 8; ++k) {
      if (k < n8) {
        float lo = __uint_as_float(uv[k] << 16);          // feat lane
        float hi = __uint_as_float(uv[k] & 0xffff0000u);  // feat lane+64
        float* base = aggS + ldv[k] * AGG_STRIDE + lane;
        atomicAdd(base, lo * av[k]);
        atomicAdd(base + 64, hi * av[k]);
      }
    }
    idx += n8;
  }
  __syncthreads();

  // ---- phase 2: MFMA linear + LeakyReLU ----
  const int tile = wave;  // 16 waves, 13 tiles
  if (tile < 13) {
    const int m = lane & 15;
    const int quad = lane >> 4;
    const int rbase = tile * 16;

    bf16x8 afrag[4];
#pragma unroll
    for (int q = 0; q < 4; ++q) {
      const float* ap = aggS + (rbase + m) * AGG_STRIDE + q * 32 + quad * 8;
#pragma unroll
      for (int j = 0; j < 8; ++j) afrag[q][j] = (short)f2bf(ap[j]);
    }

#pragma unroll
    for (int nt = 0; nt < 8; ++nt) {
      const float bv = bias[nt * 16 + m];
      f32x4 acc = {bv, bv, bv, bv};
#pragma unroll
      for (int q = 0; q < 4; ++q) {
        bf16x8 bfrag = wfrag[(nt * 4 + q) * 64 + lane];
        acc = __builtin_amdgcn_mfma_f32_16x16x32_bf16(afrag[q], bfrag, acc, 0, 0, 0);
      }
      const int col = nt * 16 + m;
#pragma unroll
      for (int i = 0; i < 4; ++i) {
        const int rr = rbase + quad * 4 + i;
        if (rr < NB_NODES) {
          const int nn = b * NB_NODES + rr;
          if (nn < N_NODES) {
            float v = acc[i];
            v = v >= 0.f ? v : v * LEAKY;
            out[(size_t)nn * DIM + col] = v;
          }
        }
      }
    }
  }
}

// ---------------------------------------------------------------------------
// Fallback path (tiny ws): atomic scatter + LDS vector linear.
// ---------------------------------------------------------------------------
__global__ __launch_bounds__(256) void scatter_kernel(
    const float* __restrict__ x, const int* __restrict__ ei,
    const float* __restrict__ attr, float* __restrict__ agg) {
  int gid = blockIdx.x * blockDim.x + threadIdx.x;
  int e = gid >> 5;
  int f = (gid & 31) * 4;
  if (e >= N_EDGES) return;
  int s = ei[e];
  int d = ei[N_EDGES + e];
  float a = attr[e];
  const float4 xv = *(const float4*)(x + (size_t)s * DIM + f);
  float* dp = agg + (size_t)d * DIM + f;
  atomicAdd(dp + 0, xv.x * a);
  atomicAdd(dp + 1, xv.y * a);
  atomicAdd(dp + 2, xv.z * a);
  atomicAdd(dp + 3, xv.w * a);
}

__global__ __launch_bounds__(256, 2) void linear_kernel(
    const float* __restrict__ agg, const float* __restrict__ W,
    const float* __restrict__ bias, float* __restrict__ out) {
  __shared__ float Rs[32 * RS_STRIDE];
  __shared__ float Ws[64 * WS_STRIDE];

  const int tid = threadIdx.x;
  const int c = (tid & 31) * 4;
  const int rg = tid >> 5;
  const size_t rowBase = (size_t)blockIdx.x * 32;

  {
    const int lr = tid >> 3;
    const int col = (tid & 7) * 16;
    const float4* src = (const float4*)(agg + (rowBase + lr) * DIM + col);
#pragma unroll
    for (int j = 0; j < 4; ++j) {
      *(float4*)(Rs + lr * RS_STRIDE + col + j * 4) = src[j];
    }
  }

  const float4 bv = *(const float4*)(bias + c);
  float4 acc0 = bv, acc1 = bv, acc2 = bv, acc3 = bv;

  for (int half = 0; half < 2; ++half) {
    __syncthreads();
    {
      const int k0 = tid >> 7;
      const int o = tid & 127;
#pragma unroll
      for (int kk = k0; kk < 64; kk += 2) {
        Ws[kk * WS_STRIDE + o] = W[o * DIM + half * 64 + kk];
      }
    }
    __syncthreads();

    const float* rs0 = Rs + (rg * 4 + 0) * RS_STRIDE + half * 64;
    const float* rs1 = Rs + (rg * 4 + 1) * RS_STRIDE + half * 64;
    const float* rs2 = Rs + (rg * 4 + 2) * RS_STRIDE + half * 64;
    const float* rs3 = Rs + (rg * 4 + 3) * RS_STRIDE + half * 64;

#pragma unroll 8
    for (int k4 = 0; k4 < 16; ++k4) {
      const float4 v0 = *(const float4*)(rs0 + k4 * 4);
      const float4 v1 = *(const float4*)(rs1 + k4 * 4);
      const float4 v2 = *(const float4*)(rs2 + k4 * 4);
      const float4 v3 = *(const float4*)(rs3 + k4 * 4);
      const float4 w0 = *(const float4*)(Ws + (k4 * 4 + 0) * WS_STRIDE + c);
      const float4 w1 = *(const float4*)(Ws + (k4 * 4 + 1) * WS_STRIDE + c);
      const float4 w2 = *(const float4*)(Ws + (k4 * 4 + 2) * WS_STRIDE + c);
      const float4 w3 = *(const float4*)(Ws + (k4 * 4 + 3) * WS_STRIDE + c);

#define FMA4(acc, v)                                               \
      acc.x += v.x * w0.x + v.y * w1.x + v.z * w2.x + v.w * w3.x;  \
      acc.y += v.x * w0.y + v.y * w1.y + v.z * w2.y + v.w * w3.y;  \
      acc.z += v.x * w0.z + v.y * w1.z + v.z * w2.z + v.w * w3.z;  \
      acc.w += v.x * w0.w + v.y * w1.w + v.z * w2.w + v.w * w3.w;
      FMA4(acc0, v0)
      FMA4(acc1, v1)
      FMA4(acc2, v2)
      FMA4(acc3, v3)
#undef FMA4
    }
  }

#define LEAKY4(acc)                                   \
  acc.x = acc.x >= 0.f ? acc.x : acc.x * LEAKY;       \
  acc.y = acc.y >= 0.f ? acc.y : acc.y * LEAKY;       \
  acc.z = acc.z >= 0.f ? acc.z : acc.z * LEAKY;       \
  acc.w = acc.w >= 0.f ? acc.w : acc.w * LEAKY;
  LEAKY4(acc0) LEAKY4(acc1) LEAKY4(acc2) LEAKY4(acc3)
#undef LEAKY4

  const int row0 = (int)rowBase + rg * 4;
  *(float4*)(out + (size_t)(row0 + 0) * DIM + c) = acc0;
  *(float4*)(out + (size_t)(row0 + 1) * DIM + c) = acc1;
  *(float4*)(out + (size_t)(row0 + 2) * DIM + c) = acc2;
  *(float4*)(out + (size_t)(row0 + 3) * DIM + c) = acc3;
}

extern "C" void kernel_launch(void* const* d_in, const int* in_sizes, int n_in,
                              void* d_out, int out_size, void* d_ws, size_t ws_size,
                              hipStream_t stream) {
  const float* x = (const float*)d_in[0];
  const int* ei = (const int*)d_in[1];  // int32
  const float* attr = (const float*)d_in[2];
  const float* W = (const float*)d_in[3];
  const float* b = (const float*)d_in[4];
  float* out = (float*)d_out;

  // Workspace layout (256B-aligned)
  const size_t offBinned = 0;                         // E int2 = 12.8 MB
  const size_t offCounts = 12800000;                  // 511*391 ushort
  const size_t offSrcOff = 13199616;                  // 511*391 int
  const size_t offWfrag  = 13998848;                  // 32 KB
  const size_t offXb     = 14031616;                  // N*64 uint = 25.6 MB
  const size_t wsNeeded  = offXb + 25600000;          // ~39.6 MB

  if (ws_size >= wsNeeded) {
    char* ws = (char*)d_ws;
    int2* binned = (int2*)(ws + offBinned);
    unsigned short* counts = (unsigned short*)(ws + offCounts);
    int* srcOff = (int*)(ws + offSrcOff);
    bf16x8* wfrag = (bf16x8*)(ws + offWfrag);
    unsigned int* xb = (unsigned int*)(ws + offXb);

    w_frag_kernel<<<8, 256, 0, stream>>>(W, wfrag);
    x2b_perm_kernel<<<25000, 256, 0, stream>>>(x, xb);
    sort_local_kernel<<<NSB, 512, 0, stream>>>(ei, attr, binned, counts, srcOff);
    fused_kernel<<<NBUCKET, 1024, 0, stream>>>(xb, binned, counts, srcOff,
                                               wfrag, b, out);
  } else {
    hipMemsetAsync(out, 0, (size_t)N_NODES * DIM * sizeof(float), stream);
    scatter_kernel<<<(N_EDGES * 32) / 256, 256, 0, stream>>>(x, ei, attr, out);
    linear_kernel<<<N_NODES / 32, 256, 0, stream>>>(out, W, b, out);
  }
}